// Round 15
// baseline (138.271 us; speedup 1.0000x reference)
//
#include <hip/hip_runtime.h>

#define BOX   256
#define KS    9
#define HALF  4
#define NPTS  20000
#define NB    16
#define NLAT  8
#define CANW  264                  // BOX + 2*HALF
#define NPBLK 2500                 // 2500 blocks * 4 waves * 32 pts = 320000
#define CANVAS_ELEMS (NB * CANW * CANW)
#define CANVAS_F4    (CANVAS_ELEMS / 4)

typedef _Float16 half8   __attribute__((ext_vector_type(8)));
typedef __fp16   fp16x2  __attribute__((ext_vector_type(2)));
typedef float    floatx4 __attribute__((ext_vector_type(4)));

// ws layout: [0,20480) 10 f16 weight mats [32][32] (A-operand form)
//   0:linamp1(k<4) 1..3:ampblock(perm) 4:lin0(k<10) 5..7:deform(perm)
//   8:T_amp (row0 = linamp2, perm cols)  9:T_d (rows0..2 = lin1a, perm cols)
// [20480,...) canvas [16][264][264] fp32
#define WH_BYTES 20480

__device__ __forceinline__ int perm_inv(int k) {
    return ((k >> 2) & 1) * 16 + (k >> 3) * 4 + (k & 3);
}

__device__ __forceinline__ half8 pack8(const float x[8]) {
    union { fp16x2 v2[4]; half8 v8; } u;
    u.v2[0] = __builtin_amdgcn_cvt_pkrtz(x[0], x[1]);
    u.v2[1] = __builtin_amdgcn_cvt_pkrtz(x[2], x[3]);
    u.v2[2] = __builtin_amdgcn_cvt_pkrtz(x[4], x[5]);
    u.v2[3] = __builtin_amdgcn_cvt_pkrtz(x[6], x[7]);
    return u.v8;
}

// ---------------------------------------------------------------------------
// prep: build 10 f16 A-operand matrices AND zero the canvas (one node).
// (identical to R14)
// ---------------------------------------------------------------------------
__global__ __launch_bounds__(256) void prep_kernel(
    const float* __restrict__ linamp1_W, const float* __restrict__ ampblock_W,
    const float* __restrict__ lin0_W, const float* __restrict__ deform_W,
    const float* __restrict__ linamp2_W, const float* __restrict__ lin1a_W,
    _Float16* __restrict__ wh, float* __restrict__ canvas)
{
    const int idx = blockIdx.x * 256 + threadIdx.x;

    if (idx < CANVAS_F4) {
        floatx4 zv = {0.f, 0.f, 0.f, 0.f};
        ((floatx4*)canvas)[idx] = zv;
    }

    if (idx < 10 * 1024) {
        const int mat = idx >> 10, rem = idx & 1023;
        const int m = rem >> 5, k = rem & 31;
        float v = 0.0f;
        if (mat == 0)      { if (k < 4)  v = linamp1_W[m * 4 + k]; }
        else if (mat <= 3) { v = ampblock_W[(mat - 1) * 1024 + m * 32 + perm_inv(k)]; }
        else if (mat == 4) { if (k < 10) v = lin0_W[m * 10 + k]; }
        else if (mat <= 7) { v = deform_W[(mat - 5) * 1024 + m * 32 + perm_inv(k)]; }
        else if (mat == 8) { if (m == 0) v = linamp2_W[perm_inv(k)]; }
        else               { if (m < 3)  v = lin1a_W[m * 32 + perm_inv(k)]; }
        wh[idx] = (_Float16)v;
    }
}

// ---------------------------------------------------------------------------
// point kernel (R15): register-resident weights + INTERLEAVED heads
// (8 independent MFMA chains per stage, deform unconditional, masked at end)
// + tail-MFMA + quad0 epilogue.  1 wave = 1 set of 32 points.
// ---------------------------------------------------------------------------
__global__ __launch_bounds__(256, 2) void point_kernel(
    const float* __restrict__ z, const float* __restrict__ r,
    const float* __restrict__ pos, const float* __restrict__ amp,
    const float* __restrict__ ampblock_b, const float* __restrict__ linamp2_b,
    const float* __restrict__ deform_b, const float* __restrict__ lin1b_W,
    const int* __restrict__ dflag, const _Float16* __restrict__ wh,
    float* __restrict__ canvas, float* __restrict__ pos_def_out,
    float* __restrict__ res_out, float* __restrict__ amp_corr_out)
{
    const int lane = threadIdx.x & 63;
    const int n    = lane & 15;
    const int quad = lane >> 4;
    const int aoff = quad * 8;
    const int s    = blockIdx.x * 4 + (threadIdx.x >> 6);   // set id 0..9999
    const int d    = *dflag;
    const floatx4 zero = {0.f, 0.f, 0.f, 0.f};

    // ======== hoisted params (loaded once per wave) ========================
    half8 wA0[4], wA1[4], wD0[4], wD1[4];
    #pragma unroll
    for (int m = 0; m < 4; ++m) {
        wA0[m] = *(const half8*)(wh + m * 1024 + n * 32 + aoff);
        wA1[m] = *(const half8*)(wh + m * 1024 + (n + 16) * 32 + aoff);
        wD0[m] = *(const half8*)(wh + (4 + m) * 1024 + n * 32 + aoff);
        wD1[m] = *(const half8*)(wh + (4 + m) * 1024 + (n + 16) * 32 + aoff);
    }
    half8 tA = *(const half8*)(wh + 8 * 1024 + n * 32 + aoff);
    half8 tD = *(const half8*)(wh + 9 * 1024 + n * 32 + aoff);

    floatx4 bA0[3], bA1[3], bD0[3], bD1[3];
    #pragma unroll
    for (int l = 0; l < 3; ++l) {
        bA0[l] = *(const floatx4*)(ampblock_b + l * 32 + quad * 4);
        bA1[l] = *(const floatx4*)(ampblock_b + l * 32 + 16 + quad * 4);
        bD0[l] = *(const floatx4*)(deform_b + l * 32 + quad * 4);
        bD1[l] = *(const floatx4*)(deform_b + l * 32 + 16 + quad * 4);
    }
    const float l2b  = linamp2_b[0];
    const float ampv = amp[0];
    float lb[9];
    #pragma unroll
    for (int i = 0; i < 9; ++i) lb[i] = lin1b_W[i];

    const int base0 = s * 32;            // 625 sets per batch: never crosses
    const int b     = base0 / NPTS;

    float zl[NLAT];
    #pragma unroll
    for (int k = 0; k < NLAT; ++k) zl[k] = z[b * NLAT + k];

    float px[2], py[2], pz[2];
    half8 bfa[2], bfd[2];
    #pragma unroll
    for (int g = 0; g < 2; ++g) {
        const int p = base0 - b * NPTS + g * 16 + n;
        px[g] = pos[3 * p + 0];
        py[g] = pos[3 * p + 1];
        pz[g] = pos[3 * p + 2];
        half8 t;
        #pragma unroll
        for (int j = 0; j < 8; ++j) t[j] = (_Float16)0.f;
        bfa[g] = t; bfd[g] = t;
        if (quad == 0) {
            bfa[g][0] = (_Float16)px[g]; bfa[g][1] = (_Float16)py[g];
            bfa[g][2] = (_Float16)pz[g]; bfa[g][3] = (_Float16)zl[7];
            bfd[g][0] = (_Float16)px[g]; bfd[g][1] = (_Float16)py[g];
            bfd[g][2] = (_Float16)pz[g]; bfd[g][3] = (_Float16)zl[0];
            bfd[g][4] = (_Float16)zl[1]; bfd[g][5] = (_Float16)zl[2];
            bfd[g][6] = (_Float16)zl[3]; bfd[g][7] = (_Float16)zl[4];
        } else if (quad == 1) {
            bfd[g][0] = (_Float16)zl[5]; bfd[g][1] = (_Float16)zl[6];
        }
    }

    // ---- stage 0: input layers of BOTH heads (8 independent MFMAs) ----
    float xA[2][8], xD[2][8];
    #pragma unroll
    for (int g = 0; g < 2; ++g) {
        floatx4 cA0 = __builtin_amdgcn_mfma_f32_16x16x32_f16(wA0[0], bfa[g], zero, 0, 0, 0);
        floatx4 cA1 = __builtin_amdgcn_mfma_f32_16x16x32_f16(wA1[0], bfa[g], zero, 0, 0, 0);
        floatx4 cD0 = __builtin_amdgcn_mfma_f32_16x16x32_f16(wD0[0], bfd[g], zero, 0, 0, 0);
        floatx4 cD1 = __builtin_amdgcn_mfma_f32_16x16x32_f16(wD1[0], bfd[g], zero, 0, 0, 0);
        #pragma unroll
        for (int rr = 0; rr < 4; ++rr) {
            xA[g][rr] = cA0[rr]; xA[g][4 + rr] = cA1[rr];
            xD[g][rr] = cD0[rr]; xD[g][4 + rr] = cD1[rr];
        }
    }

    // ---- residual layers, both heads interleaved ----
    #pragma unroll
    for (int l = 0; l < 3; ++l) {
        #pragma unroll
        for (int g = 0; g < 2; ++g) {
            half8 hA = pack8(xA[g]);
            half8 hD = pack8(xD[g]);
            floatx4 dA0 = __builtin_amdgcn_mfma_f32_16x16x32_f16(wA0[1 + l], hA, bA0[l], 0, 0, 0);
            floatx4 dA1 = __builtin_amdgcn_mfma_f32_16x16x32_f16(wA1[1 + l], hA, bA1[l], 0, 0, 0);
            floatx4 dD0 = __builtin_amdgcn_mfma_f32_16x16x32_f16(wD0[1 + l], hD, bD0[l], 0, 0, 0);
            floatx4 dD1 = __builtin_amdgcn_mfma_f32_16x16x32_f16(wD1[1 + l], hD, bD1[l], 0, 0, 0);
            #pragma unroll
            for (int rr = 0; rr < 4; ++rr) {
                xA[g][rr]     += fmaxf(dA0[rr], 0.f);
                xA[g][4 + rr] += fmaxf(dA1[rr], 0.f);
                xD[g][rr]     += fmaxf(dD0[rr], 0.f);
                xD[g][4 + rr] += fmaxf(dD1[rr], 0.f);
            }
        }
    }

    // ---- tails via MFMA: quad0 regs hold per-point dots ----
    floatx4 dA[2], dD[2];
    #pragma unroll
    for (int g = 0; g < 2; ++g) {
        half8 hA = pack8(xA[g]);
        half8 hD = pack8(xD[g]);
        dA[g] = __builtin_amdgcn_mfma_f32_16x16x32_f16(tA, hA, zero, 0, 0, 0);
        dD[g] = __builtin_amdgcn_mfma_f32_16x16x32_f16(tD, hD, zero, 0, 0, 0);
    }

    // ---- epilogue: everything lives in quad 0; deform masked by d ----
    if (quad == 0) {
        const float* rb = r + b * 9;
        const float r00 = rb[0], r01 = rb[1], r02 = rb[2];
        const float r10 = rb[3], r11 = rb[4], r12 = rb[5];
        #pragma unroll
        for (int g = 0; g < 2; ++g) {
            const int bp = base0 + g * 16 + n;
            const float corr = 1.f / (1.f + __expf(-(dA[g][0] + l2b)));
            float r0 = 0.f, r1 = 0.f, r2 = 0.f;
            if (d > 0) {
                const float t0 = 1.f - 2.f / (__expf(2.f * dD[g][0]) + 1.f);
                const float t1 = 1.f - 2.f / (__expf(2.f * dD[g][1]) + 1.f);
                const float t2 = 1.f - 2.f / (__expf(2.f * dD[g][2]) + 1.f);
                r0 = t0 * lb[0] + t1 * lb[1] + t2 * lb[2];
                r1 = t0 * lb[3] + t1 * lb[4] + t2 * lb[5];
                r2 = t0 * lb[6] + t1 * lb[7] + t2 * lb[8];
            }
            const float pdx = px[g] + r0, pdy = py[g] + r1, pdz = pz[g] + r2;

            pos_def_out[3 * bp + 0] = pdx;
            pos_def_out[3 * bp + 1] = pdy;
            pos_def_out[3 * bp + 2] = pdz;
            res_out[3 * bp + 0] = r0;
            res_out[3 * bp + 1] = r1;
            res_out[3 * bp + 2] = r2;
            amp_corr_out[bp] = corr;

            const float pjx = r00 * pdx + r01 * pdy + r02 * pdz;
            const float pjy = r10 * pdx + r11 * pdy + r12 * pdz;
            const int cx = (int)rintf((pjx + 0.5f) * (float)(BOX - 1));
            const int cy = (int)rintf((pjy + 0.5f) * (float)(BOX - 1));
            if (cx >= -HALF && cx <= BOX - 1 + HALF &&
                cy >= -HALF && cy <= BOX - 1 + HALF) {
                atomicAdd(canvas + ((size_t)b * CANW + (cy + HALF)) * CANW + (cx + HALF),
                          ampv * corr);
            }
        }
    }
}

// ---------------------------------------------------------------------------
// fused separable conv: one block per (b, 8-row output stripe) = 512 blocks.
// ---------------------------------------------------------------------------
__global__ __launch_bounds__(256) void conv_kernel(
    const float* __restrict__ canvas, const float* __restrict__ k2,
    float* __restrict__ img)
{
    __shared__ float t_lds[16][256];
    const int x  = threadIdx.x;
    const int b  = blockIdx.x >> 5;
    const int y0 = (blockIdx.x & 31) * 8;

    float g[KS];
    #pragma unroll
    for (int i = 0; i < KS; ++i) {
        float sg = 0.f;
        #pragma unroll
        for (int j = 0; j < KS; ++j) sg += k2[i * KS + j];
        g[i] = sg;
    }

    const float* cb = canvas + (size_t)b * CANW * CANW;
    #pragma unroll 4
    for (int rr = 0; rr < 16; ++rr) {
        const float* row = cb + (size_t)(y0 + rr) * CANW;
        float s = 0.f;
        #pragma unroll
        for (int i = 0; i < KS; ++i) s = fmaf(g[i], row[x + (KS - 1) - i], s);
        t_lds[rr][x] = s;
    }
    __syncthreads();

    float* ib = img + ((size_t)b * BOX + y0) * BOX;
    #pragma unroll 4
    for (int yy = 0; yy < 8; ++yy) {
        float s = 0.f;
        #pragma unroll
        for (int i = 0; i < KS; ++i) s = fmaf(g[i], t_lds[yy + (KS - 1) - i][x], s);
        ib[yy * BOX + x] = s;
    }
}

extern "C" void kernel_launch(void* const* d_in, const int* in_sizes, int n_in,
                              void* d_out, int out_size, void* d_ws, size_t ws_size,
                              hipStream_t stream) {
    const float* z          = (const float*)d_in[0];
    const float* r          = (const float*)d_in[1];
    const float* pos        = (const float*)d_in[2];
    const float* amp        = (const float*)d_in[3];
    const float* linamp1_W  = (const float*)d_in[4];
    const float* ampblock_W = (const float*)d_in[5];
    const float* ampblock_b = (const float*)d_in[6];
    const float* linamp2_W  = (const float*)d_in[7];
    const float* linamp2_b  = (const float*)d_in[8];
    const float* lin0_W     = (const float*)d_in[9];
    const float* deform_W   = (const float*)d_in[10];
    const float* deform_b   = (const float*)d_in[11];
    const float* lin1a_W    = (const float*)d_in[12];
    const float* lin1b_W    = (const float*)d_in[13];
    const float* k2         = (const float*)d_in[14];
    const int*   dflag      = (const int*)d_in[15];

    float* out = (float*)d_out;
    float* img          = out;                               // [16,256,256]
    float* pos_def_out  = out + (size_t)NB * BOX * BOX;
    float* res_out      = pos_def_out + (size_t)NB * NPTS * 3;
    float* amp_corr_out = res_out + (size_t)NB * NPTS * 3;

    _Float16* wh     = (_Float16*)d_ws;
    float*    canvas = (float*)((char*)d_ws + WH_BYTES);     // [16,264,264]

    // prep + canvas zero in one node (grid sized for the canvas clear)
    prep_kernel<<<(CANVAS_F4 + 255) / 256, 256, 0, stream>>>(
        linamp1_W, ampblock_W, lin0_W, deform_W, linamp2_W, lin1a_W,
        wh, canvas);

    point_kernel<<<NPBLK, 256, 0, stream>>>(
        z, r, pos, amp, ampblock_b, linamp2_b, deform_b, lin1b_W,
        dflag, wh, canvas, pos_def_out, res_out, amp_corr_out);

    conv_kernel<<<NB * 32, 256, 0, stream>>>(canvas, k2, img);
}

// Round 16
// 127.984 us; speedup vs baseline: 1.0804x; 1.0804x over previous
//
#include <hip/hip_runtime.h>

#define BOX   256
#define KS    9
#define HALF  4
#define NPTS  20000
#define NB    16
#define NLAT  8
#define CANW  264                  // BOX + 2*HALF
#define NPBLK 1250                 // 1250 blocks * 4 waves * 2 sets * 32 pts = 320000
#define CANVAS_ELEMS (NB * CANW * CANW)
#define CANVAS_F4    (CANVAS_ELEMS / 4)

typedef _Float16 half8   __attribute__((ext_vector_type(8)));
typedef __fp16   fp16x2  __attribute__((ext_vector_type(2)));
typedef float    floatx4 __attribute__((ext_vector_type(4)));

// ws layout: [0,20480) 10 f16 weight mats [32][32] (A-operand form)
//   0:linamp1(k<4) 1..3:ampblock(perm) 4:lin0(k<10) 5..7:deform(perm)
//   8:T_amp (rows 0 AND 4 = linamp2, perm cols)
//   9:T_d   (rows 0..2 AND 4..6 = lin1a, perm cols)
//   Row duplication puts each group's tail dots in BOTH quad0 and quad1
//   (C-layout row = quad*4 + reg), enabling the dual-quad epilogue.
// [20480,...) canvas [16][264][264] fp32
#define WH_BYTES 20480

__device__ __forceinline__ int perm_inv(int k) {
    return ((k >> 2) & 1) * 16 + (k >> 3) * 4 + (k & 3);
}

__device__ __forceinline__ half8 pack8(const float x[8]) {
    union { fp16x2 v2[4]; half8 v8; } u;
    u.v2[0] = __builtin_amdgcn_cvt_pkrtz(x[0], x[1]);
    u.v2[1] = __builtin_amdgcn_cvt_pkrtz(x[2], x[3]);
    u.v2[2] = __builtin_amdgcn_cvt_pkrtz(x[4], x[5]);
    u.v2[3] = __builtin_amdgcn_cvt_pkrtz(x[6], x[7]);
    return u.v8;
}

// ---------------------------------------------------------------------------
// prep: build 10 f16 A-operand matrices AND zero the canvas (one node).
// ---------------------------------------------------------------------------
__global__ __launch_bounds__(256) void prep_kernel(
    const float* __restrict__ linamp1_W, const float* __restrict__ ampblock_W,
    const float* __restrict__ lin0_W, const float* __restrict__ deform_W,
    const float* __restrict__ linamp2_W, const float* __restrict__ lin1a_W,
    _Float16* __restrict__ wh, float* __restrict__ canvas)
{
    const int idx = blockIdx.x * 256 + threadIdx.x;

    if (idx < CANVAS_F4) {
        floatx4 zv = {0.f, 0.f, 0.f, 0.f};
        ((floatx4*)canvas)[idx] = zv;
    }

    if (idx < 10 * 1024) {
        const int mat = idx >> 10, rem = idx & 1023;
        const int m = rem >> 5, k = rem & 31;
        float v = 0.0f;
        if (mat == 0)      { if (k < 4)  v = linamp1_W[m * 4 + k]; }
        else if (mat <= 3) { v = ampblock_W[(mat - 1) * 1024 + m * 32 + perm_inv(k)]; }
        else if (mat == 4) { if (k < 10) v = lin0_W[m * 10 + k]; }
        else if (mat <= 7) { v = deform_W[(mat - 5) * 1024 + m * 32 + perm_inv(k)]; }
        else if (mat == 8) { if (m == 0 || m == 4) v = linamp2_W[perm_inv(k)]; }
        else               { if (m < 3)            v = lin1a_W[m * 32 + perm_inv(k)];
                             else if (m >= 4 && m < 7) v = lin1a_W[(m - 4) * 32 + perm_inv(k)]; }
        wh[idx] = (_Float16)v;
    }
}

// ---------------------------------------------------------------------------
// point kernel (R16): R14 (register-resident weights, 2-set loop, tail-MFMA)
// + DUAL-QUAD epilogue (quad0 -> group 0, quad1 -> group 1).
// ---------------------------------------------------------------------------
__global__ __launch_bounds__(256, 2) void point_kernel(
    const float* __restrict__ z, const float* __restrict__ r,
    const float* __restrict__ pos, const float* __restrict__ amp,
    const float* __restrict__ ampblock_b, const float* __restrict__ linamp2_b,
    const float* __restrict__ deform_b, const float* __restrict__ lin1b_W,
    const int* __restrict__ dflag, const _Float16* __restrict__ wh,
    float* __restrict__ canvas, float* __restrict__ pos_def_out,
    float* __restrict__ res_out, float* __restrict__ amp_corr_out)
{
    const int lane = threadIdx.x & 63;
    const int n    = lane & 15;
    const int quad = lane >> 4;
    const int aoff = quad * 8;
    const int w    = blockIdx.x * 4 + (threadIdx.x >> 6);   // wave id 0..4999
    const int d    = *dflag;
    const floatx4 zero = {0.f, 0.f, 0.f, 0.f};

    // ======== hoisted params (loaded once per wave) ========================
    half8 wA0[4], wA1[4], wD0[4], wD1[4];
    #pragma unroll
    for (int m = 0; m < 4; ++m) {
        wA0[m] = *(const half8*)(wh + m * 1024 + n * 32 + aoff);
        wA1[m] = *(const half8*)(wh + m * 1024 + (n + 16) * 32 + aoff);
        wD0[m] = *(const half8*)(wh + (4 + m) * 1024 + n * 32 + aoff);
        wD1[m] = *(const half8*)(wh + (4 + m) * 1024 + (n + 16) * 32 + aoff);
    }
    half8 tA = *(const half8*)(wh + 8 * 1024 + n * 32 + aoff);
    half8 tD = *(const half8*)(wh + 9 * 1024 + n * 32 + aoff);

    floatx4 bA0[3], bA1[3], bD0[3], bD1[3];
    #pragma unroll
    for (int l = 0; l < 3; ++l) {
        bA0[l] = *(const floatx4*)(ampblock_b + l * 32 + quad * 4);
        bA1[l] = *(const floatx4*)(ampblock_b + l * 32 + 16 + quad * 4);
        bD0[l] = *(const floatx4*)(deform_b + l * 32 + quad * 4);
        bD1[l] = *(const floatx4*)(deform_b + l * 32 + 16 + quad * 4);
    }
    const float l2b  = linamp2_b[0];
    const float ampv = amp[0];
    float lb[9];
    #pragma unroll
    for (int i = 0; i < 9; ++i) lb[i] = lin1b_W[i];

    // ======== loop over 2 consecutive sets of 32 points ====================
    for (int it = 0; it < 2; ++it) {
        const int s     = w * 2 + it;        // set id 0..9999
        const int base0 = s * 32;
        const int b     = base0 / NPTS;

        float zl[NLAT];
        #pragma unroll
        for (int k = 0; k < NLAT; ++k) zl[k] = z[b * NLAT + k];

        float px[2], py[2], pz[2];
        half8 bfa[2], bfd[2];
        #pragma unroll
        for (int g = 0; g < 2; ++g) {
            const int p = base0 - b * NPTS + g * 16 + n;
            px[g] = pos[3 * p + 0];
            py[g] = pos[3 * p + 1];
            pz[g] = pos[3 * p + 2];
            half8 t;
            #pragma unroll
            for (int j = 0; j < 8; ++j) t[j] = (_Float16)0.f;
            bfa[g] = t; bfd[g] = t;
            if (quad == 0) {
                bfa[g][0] = (_Float16)px[g]; bfa[g][1] = (_Float16)py[g];
                bfa[g][2] = (_Float16)pz[g]; bfa[g][3] = (_Float16)zl[7];
                bfd[g][0] = (_Float16)px[g]; bfd[g][1] = (_Float16)py[g];
                bfd[g][2] = (_Float16)pz[g]; bfd[g][3] = (_Float16)zl[0];
                bfd[g][4] = (_Float16)zl[1]; bfd[g][5] = (_Float16)zl[2];
                bfd[g][6] = (_Float16)zl[3]; bfd[g][7] = (_Float16)zl[4];
            } else if (quad == 1) {
                bfd[g][0] = (_Float16)zl[5]; bfd[g][1] = (_Float16)zl[6];
            }
        }

        // ---- amplitude head ----
        float xB[2][8];
        #pragma unroll
        for (int g = 0; g < 2; ++g) {
            floatx4 c0 = __builtin_amdgcn_mfma_f32_16x16x32_f16(wA0[0], bfa[g], zero, 0, 0, 0);
            floatx4 c1 = __builtin_amdgcn_mfma_f32_16x16x32_f16(wA1[0], bfa[g], zero, 0, 0, 0);
            #pragma unroll
            for (int rr = 0; rr < 4; ++rr) { xB[g][rr] = c0[rr]; xB[g][4 + rr] = c1[rr]; }
        }
        #pragma unroll
        for (int l = 0; l < 3; ++l) {
            #pragma unroll
            for (int g = 0; g < 2; ++g) {
                half8 hf = pack8(xB[g]);
                floatx4 d0 = __builtin_amdgcn_mfma_f32_16x16x32_f16(wA0[1 + l], hf, bA0[l], 0, 0, 0);
                floatx4 d1 = __builtin_amdgcn_mfma_f32_16x16x32_f16(wA1[1 + l], hf, bA1[l], 0, 0, 0);
                #pragma unroll
                for (int rr = 0; rr < 4; ++rr) {
                    xB[g][rr]     += fmaxf(d0[rr], 0.f);
                    xB[g][4 + rr] += fmaxf(d1[rr], 0.f);
                }
            }
        }
        // amp tail via MFMA: rows 0 and 4 both = linamp2 -> quad0 AND quad1
        floatx4 dA[2];
        #pragma unroll
        for (int g = 0; g < 2; ++g) {
            half8 hf = pack8(xB[g]);
            dA[g] = __builtin_amdgcn_mfma_f32_16x16x32_f16(tA, hf, zero, 0, 0, 0);
        }

        // ---- deformation head ----
        floatx4 dD[2] = {zero, zero};
        if (d > 0) {
            #pragma unroll
            for (int g = 0; g < 2; ++g) {
                floatx4 c0 = __builtin_amdgcn_mfma_f32_16x16x32_f16(wD0[0], bfd[g], zero, 0, 0, 0);
                floatx4 c1 = __builtin_amdgcn_mfma_f32_16x16x32_f16(wD1[0], bfd[g], zero, 0, 0, 0);
                #pragma unroll
                for (int rr = 0; rr < 4; ++rr) { xB[g][rr] = c0[rr]; xB[g][4 + rr] = c1[rr]; }
            }
            #pragma unroll
            for (int l = 0; l < 3; ++l) {
                #pragma unroll
                for (int g = 0; g < 2; ++g) {
                    half8 hf = pack8(xB[g]);
                    floatx4 d0 = __builtin_amdgcn_mfma_f32_16x16x32_f16(wD0[1 + l], hf, bD0[l], 0, 0, 0);
                    floatx4 d1 = __builtin_amdgcn_mfma_f32_16x16x32_f16(wD1[1 + l], hf, bD1[l], 0, 0, 0);
                    #pragma unroll
                    for (int rr = 0; rr < 4; ++rr) {
                        xB[g][rr]     += fmaxf(d0[rr], 0.f);
                        xB[g][4 + rr] += fmaxf(d1[rr], 0.f);
                    }
                }
            }
            #pragma unroll
            for (int g = 0; g < 2; ++g) {
                half8 hf = pack8(xB[g]);
                dD[g] = __builtin_amdgcn_mfma_f32_16x16x32_f16(tD, hf, zero, 0, 0, 0);
            }
        }

        // ---- epilogue: quad0 -> group 0, quad1 -> group 1 (parallel) ----
        if (quad < 2) {
            const int g = quad;
            const float* rb = r + b * 9;
            const float r00 = rb[0], r01 = rb[1], r02 = rb[2];
            const float r10 = rb[3], r11 = rb[4], r12 = rb[5];
            const int bp = base0 + g * 16 + n;
            const float corr = 1.f / (1.f + __expf(-(dA[g][0] + l2b)));
            float r0 = 0.f, r1 = 0.f, r2 = 0.f;
            if (d > 0) {
                const float t0 = 1.f - 2.f / (__expf(2.f * dD[g][0]) + 1.f);
                const float t1 = 1.f - 2.f / (__expf(2.f * dD[g][1]) + 1.f);
                const float t2 = 1.f - 2.f / (__expf(2.f * dD[g][2]) + 1.f);
                r0 = t0 * lb[0] + t1 * lb[1] + t2 * lb[2];
                r1 = t0 * lb[3] + t1 * lb[4] + t2 * lb[5];
                r2 = t0 * lb[6] + t1 * lb[7] + t2 * lb[8];
            }
            const float pdx = px[g] + r0, pdy = py[g] + r1, pdz = pz[g] + r2;

            pos_def_out[3 * bp + 0] = pdx;
            pos_def_out[3 * bp + 1] = pdy;
            pos_def_out[3 * bp + 2] = pdz;
            res_out[3 * bp + 0] = r0;
            res_out[3 * bp + 1] = r1;
            res_out[3 * bp + 2] = r2;
            amp_corr_out[bp] = corr;

            const float pjx = r00 * pdx + r01 * pdy + r02 * pdz;
            const float pjy = r10 * pdx + r11 * pdy + r12 * pdz;
            const int cx = (int)rintf((pjx + 0.5f) * (float)(BOX - 1));
            const int cy = (int)rintf((pjy + 0.5f) * (float)(BOX - 1));
            if (cx >= -HALF && cx <= BOX - 1 + HALF &&
                cy >= -HALF && cy <= BOX - 1 + HALF) {
                atomicAdd(canvas + ((size_t)b * CANW + (cy + HALF)) * CANW + (cx + HALF),
                          ampv * corr);
            }
        }
    }
}

// ---------------------------------------------------------------------------
// fused separable conv: one block per (b, 8-row output stripe) = 512 blocks.
// ---------------------------------------------------------------------------
__global__ __launch_bounds__(256) void conv_kernel(
    const float* __restrict__ canvas, const float* __restrict__ k2,
    float* __restrict__ img)
{
    __shared__ float t_lds[16][256];
    const int x  = threadIdx.x;
    const int b  = blockIdx.x >> 5;
    const int y0 = (blockIdx.x & 31) * 8;

    float g[KS];
    #pragma unroll
    for (int i = 0; i < KS; ++i) {
        float sg = 0.f;
        #pragma unroll
        for (int j = 0; j < KS; ++j) sg += k2[i * KS + j];
        g[i] = sg;
    }

    const float* cb = canvas + (size_t)b * CANW * CANW;
    #pragma unroll 4
    for (int rr = 0; rr < 16; ++rr) {
        const float* row = cb + (size_t)(y0 + rr) * CANW;
        float s = 0.f;
        #pragma unroll
        for (int i = 0; i < KS; ++i) s = fmaf(g[i], row[x + (KS - 1) - i], s);
        t_lds[rr][x] = s;
    }
    __syncthreads();

    float* ib = img + ((size_t)b * BOX + y0) * BOX;
    #pragma unroll 4
    for (int yy = 0; yy < 8; ++yy) {
        float s = 0.f;
        #pragma unroll
        for (int i = 0; i < KS; ++i) s = fmaf(g[i], t_lds[yy + (KS - 1) - i][x], s);
        ib[yy * BOX + x] = s;
    }
}

extern "C" void kernel_launch(void* const* d_in, const int* in_sizes, int n_in,
                              void* d_out, int out_size, void* d_ws, size_t ws_size,
                              hipStream_t stream) {
    const float* z          = (const float*)d_in[0];
    const float* r          = (const float*)d_in[1];
    const float* pos        = (const float*)d_in[2];
    const float* amp        = (const float*)d_in[3];
    const float* linamp1_W  = (const float*)d_in[4];
    const float* ampblock_W = (const float*)d_in[5];
    const float* ampblock_b = (const float*)d_in[6];
    const float* linamp2_W  = (const float*)d_in[7];
    const float* linamp2_b  = (const float*)d_in[8];
    const float* lin0_W     = (const float*)d_in[9];
    const float* deform_W   = (const float*)d_in[10];
    const float* deform_b   = (const float*)d_in[11];
    const float* lin1a_W    = (const float*)d_in[12];
    const float* lin1b_W    = (const float*)d_in[13];
    const float* k2         = (const float*)d_in[14];
    const int*   dflag      = (const int*)d_in[15];

    float* out = (float*)d_out;
    float* img          = out;                               // [16,256,256]
    float* pos_def_out  = out + (size_t)NB * BOX * BOX;
    float* res_out      = pos_def_out + (size_t)NB * NPTS * 3;
    float* amp_corr_out = res_out + (size_t)NB * NPTS * 3;

    _Float16* wh     = (_Float16*)d_ws;
    float*    canvas = (float*)((char*)d_ws + WH_BYTES);     // [16,264,264]

    // prep + canvas zero in one node (grid sized for the canvas clear)
    prep_kernel<<<(CANVAS_F4 + 255) / 256, 256, 0, stream>>>(
        linamp1_W, ampblock_W, lin0_W, deform_W, linamp2_W, lin1a_W,
        wh, canvas);

    point_kernel<<<NPBLK, 256, 0, stream>>>(
        z, r, pos, amp, ampblock_b, linamp2_b, deform_b, lin1b_W,
        dflag, wh, canvas, pos_def_out, res_out, amp_corr_out);

    conv_kernel<<<NB * 32, 256, 0, stream>>>(canvas, k2, img);
}